// Round 5
// baseline (150.571 us; speedup 1.0000x reference)
//
#include <hip/hip_runtime.h>

// Trilinear interp of [64,64,64,64] fp32 volume at 200k points.
// R5: bucket-then-tile. One-pass fixed-capacity bucket scatter (4096 buckets
// of 4^3 voxels, cap 128, overflow list), then one block per bucket stages the
// 5^3-voxel x 64ch neighborhood (31.25KB) into LDS with dense coalesced loads
// and serves all its points' 8 corners from LDS. Turns 410MB of random gathers
// into 128MB of streaming reads + LDS traffic. Per-point math identical to R1.

#define NBUCK   4096          // 16^3 buckets of 4^3 voxels
#define CAP     128           // mean occupancy 48.8; P(overflow) ~ 0
#define OVCAP   8192
#define TILE_F4 2000          // 5*5*5 voxels * 16 float4

typedef float __attribute__((ext_vector_type(4))) fx4;

__device__ __forceinline__ float4 f4mul(float4 a, float s) {
    return make_float4(a.x * s, a.y * s, a.z * s, a.w * s);
}
__device__ __forceinline__ float4 f4fma(float4 a, float s, float4 acc) {
    return make_float4(fmaf(a.x, s, acc.x), fmaf(a.y, s, acc.y),
                       fmaf(a.z, s, acc.z), fmaf(a.w, s, acc.w));
}

__global__ __launch_bounds__(256) void scatter_kernel(
    const float* __restrict__ coords, int* __restrict__ counts,
    float4* __restrict__ buckets, float4* __restrict__ overflow, int n)
{
    int p = blockIdx.x * 256 + threadIdx.x;
    if (p >= n) return;
    float xs = coords[3 * p + 0] * 0.5f;
    float ys = coords[3 * p + 1] * 0.5f;
    float zs = coords[3 * p + 2] * 0.5f;
    int vx = (int)floorf(xs), vy = (int)floorf(ys), vz = (int)floorf(zs);
    int bucket = ((vx >> 2) << 8) | ((vy >> 2) << 4) | (vz >> 2);
    int slot = atomicAdd(&counts[bucket], 1);
    float4 v = make_float4(xs, ys, zs, __int_as_float(p));
    if (slot < CAP) {
        buckets[bucket * CAP + slot] = v;
    } else {
        int o = atomicAdd(&counts[NBUCK], 1);
        if (o < OVCAP) overflow[o] = v;
    }
}

__global__ __launch_bounds__(256) void gather_kernel(
    const float* __restrict__ img, const int* __restrict__ counts,
    const float4* __restrict__ buckets, const float4* __restrict__ overflow,
    float* __restrict__ out)
{
    const float4* __restrict__ imgv = (const float4*)img;
    int cvec = threadIdx.x & 15;
    int grp  = threadIdx.x >> 4;          // 0..15

    if (blockIdx.x < NBUCK) {
        __shared__ float4 tile[TILE_F4];
        // XCD chunk swizzle: 8 XCDs x 512 contiguous buckets each
        int bucket = (blockIdx.x & 7) * 512 + (blockIdx.x >> 3);
        int bx0 = (bucket >> 8) << 2;
        int by0 = ((bucket >> 4) & 15) << 2;
        int bz0 = (bucket & 15) << 2;

        // stage 5x5x5 voxel neighborhood (clamped at volume edge)
        for (int f = threadIdx.x; f < TILE_F4; f += 256) {
            int tv = f >> 4, c = f & 15;
            int lz = tv % 5, t2 = tv / 5;
            int ly = t2 % 5, lx = t2 / 5;
            int gx = min(bx0 + lx, 63), gy = min(by0 + ly, 63), gz = min(bz0 + lz, 63);
            tile[f] = imgv[(((((gx << 6) + gy) << 6) + gz) << 4) + c];
        }
        int cnt = min(counts[bucket], CAP);
        __syncthreads();

        for (int i = grp; i < cnt; i += 16) {
            float4 cs = buckets[bucket * CAP + i];
            float x = cs.x, y = cs.y, z = cs.z;
            int p = __float_as_int(cs.w);

            float fx1 = floorf(x), fx2 = fminf(ceilf(x), 63.0f);
            float fy1 = floorf(y), fy2 = fminf(ceilf(y), 63.0f);
            float fz1 = floorf(z), fz2 = fminf(ceilf(z), 63.0f);

            int lx1 = (int)fx1 - bx0, lx2 = (int)fx2 - bx0;   // 0..4
            int ly1 = (int)fy1 - by0, ly2 = (int)fy2 - by0;
            int lz1 = (int)fz1 - bz0, lz2 = (int)fz2 - bz0;
            int ax1 = lx1 * 25, ax2 = lx2 * 25;
            int ay1 = ly1 * 5,  ay2 = ly2 * 5;

            float4 q111 = tile[((ax1 + ay1 + lz1) << 4) + cvec];
            float4 q211 = tile[((ax2 + ay1 + lz1) << 4) + cvec];
            float4 q121 = tile[((ax1 + ay2 + lz1) << 4) + cvec];
            float4 q221 = tile[((ax2 + ay2 + lz1) << 4) + cvec];
            float4 q112 = tile[((ax1 + ay1 + lz2) << 4) + cvec];
            float4 q212 = tile[((ax2 + ay1 + lz2) << 4) + cvec];
            float4 q122 = tile[((ax1 + ay2 + lz2) << 4) + cvec];
            float4 q222 = tile[((ax2 + ay2 + lz2) << 4) + cvec];

            float wx = x - fx1, wxc = fx2 - x;
            float wy = y - fy1, wyc = fy2 - y;
            float wz = z - fz1, wzc = fz2 - z;

            float4 ly1v = f4fma(f4fma(q221, wx, f4mul(q121, wxc)), wy,
                                f4mul(f4fma(q211, wx, f4mul(q111, wxc)), wyc));
            float4 ly2v = f4fma(f4fma(q222, wx, f4mul(q122, wxc)), wy,
                                f4mul(f4fma(q212, wx, f4mul(q112, wxc)), wyc));
            float4 res = f4fma(ly2v, wz, f4mul(ly1v, wzc));

            fx4 r; r.x = res.x; r.y = res.y; r.z = res.z; r.w = res.w;
            __builtin_nontemporal_store(r, (fx4*)out + (p << 4) + cvec);
        }
    } else {
        // overflow points (normally zero): direct global gather
        int ob = blockIdx.x - NBUCK;            // 0..31
        int cnt = min(counts[NBUCK], OVCAP);
        for (int i = (ob << 4) + grp; i < cnt; i += 32 * 16) {
            float4 cs = overflow[i];
            float x = cs.x, y = cs.y, z = cs.z;
            int p = __float_as_int(cs.w);

            float fx1 = floorf(x), fx2 = fminf(ceilf(x), 63.0f);
            float fy1 = floorf(y), fy2 = fminf(ceilf(y), 63.0f);
            float fz1 = floorf(z), fz2 = fminf(ceilf(z), 63.0f);

            int bx1 = ((int)fx1) << 12, bx2 = ((int)fx2) << 12;
            int by1 = ((int)fy1) << 6,  by2 = ((int)fy2) << 6;
            int iz1 = (int)fz1, iz2 = (int)fz2;

            float4 q111 = imgv[((bx1 + by1 + iz1) << 4) + cvec];
            float4 q211 = imgv[((bx2 + by1 + iz1) << 4) + cvec];
            float4 q121 = imgv[((bx1 + by2 + iz1) << 4) + cvec];
            float4 q221 = imgv[((bx2 + by2 + iz1) << 4) + cvec];
            float4 q112 = imgv[((bx1 + by1 + iz2) << 4) + cvec];
            float4 q212 = imgv[((bx2 + by1 + iz2) << 4) + cvec];
            float4 q122 = imgv[((bx1 + by2 + iz2) << 4) + cvec];
            float4 q222 = imgv[((bx2 + by2 + iz2) << 4) + cvec];

            float wx = x - fx1, wxc = fx2 - x;
            float wy = y - fy1, wyc = fy2 - y;
            float wz = z - fz1, wzc = fz2 - z;

            float4 ly1v = f4fma(f4fma(q221, wx, f4mul(q121, wxc)), wy,
                                f4mul(f4fma(q211, wx, f4mul(q111, wxc)), wyc));
            float4 ly2v = f4fma(f4fma(q222, wx, f4mul(q122, wxc)), wy,
                                f4mul(f4fma(q212, wx, f4mul(q112, wxc)), wyc));
            float4 res = f4fma(ly2v, wz, f4mul(ly1v, wzc));

            fx4 r; r.x = res.x; r.y = res.y; r.z = res.z; r.w = res.w;
            __builtin_nontemporal_store(r, (fx4*)out + (p << 4) + cvec);
        }
    }
}

// Fallback (R1 kernel) if workspace too small.
__global__ __launch_bounds__(256) void trilerp_kernel(
    const float* __restrict__ img, const float* __restrict__ coords,
    float* __restrict__ out, int n_points)
{
    int tid = blockIdx.x * 256 + threadIdx.x;
    int p = tid >> 4;
    if (p >= n_points) return;
    int cvec = tid & 15;

    float x = coords[3 * p + 0] * 0.5f;
    float y = coords[3 * p + 1] * 0.5f;
    float z = coords[3 * p + 2] * 0.5f;

    float fx1 = floorf(x), fx2 = fminf(ceilf(x), 63.0f);
    float fy1 = floorf(y), fy2 = fminf(ceilf(y), 63.0f);
    float fz1 = floorf(z), fz2 = fminf(ceilf(z), 63.0f);

    float wx = x - fx1, wxc = fx2 - x;
    float wy = y - fy1, wyc = fy2 - y;
    float wz = z - fz1, wzc = fz2 - z;

    const float4* __restrict__ imgv = (const float4*)img;
    int bx1 = ((int)fx1) << 12, bx2 = ((int)fx2) << 12;
    int by1 = ((int)fy1) << 6,  by2 = ((int)fy2) << 6;
    int iz1 = (int)fz1, iz2 = (int)fz2;

    float4 q11 = imgv[((bx1 + by1 + iz1) << 4) + cvec];
    float4 q21 = imgv[((bx2 + by1 + iz1) << 4) + cvec];
    float4 q12 = imgv[((bx1 + by2 + iz1) << 4) + cvec];
    float4 q22 = imgv[((bx2 + by2 + iz1) << 4) + cvec];
    float4 ly1 = f4fma(f4fma(q22, wx, f4mul(q12, wxc)), wy,
                       f4mul(f4fma(q21, wx, f4mul(q11, wxc)), wyc));

    q11 = imgv[((bx1 + by1 + iz2) << 4) + cvec];
    q21 = imgv[((bx2 + by1 + iz2) << 4) + cvec];
    q12 = imgv[((bx1 + by2 + iz2) << 4) + cvec];
    q22 = imgv[((bx2 + by2 + iz2) << 4) + cvec];
    float4 ly2 = f4fma(f4fma(q22, wx, f4mul(q12, wxc)), wy,
                       f4mul(f4fma(q21, wx, f4mul(q11, wxc)), wyc));

    float4 res = f4fma(ly2, wz, f4mul(ly1, wzc));
    ((float4*)out)[(p << 4) + cvec] = res;
}

extern "C" void kernel_launch(void* const* d_in, const int* in_sizes, int n_in,
                              void* d_out, int out_size, void* d_ws, size_t ws_size,
                              hipStream_t stream) {
    const float* img    = (const float*)d_in[0];   // [1,64,64,64,64]
    const float* coords = (const float*)d_in[1];   // [1,N,3]
    float* out = (float*)d_out;                    // [1,N,64]
    int n = in_sizes[1] / 3;

    size_t counts_bytes = 32768;                              // 4097 ints, padded
    size_t buckets_off  = counts_bytes;
    size_t buckets_bytes = (size_t)NBUCK * CAP * sizeof(float4);   // 8 MB
    size_t overflow_off = buckets_off + buckets_bytes;
    size_t need = overflow_off + (size_t)OVCAP * sizeof(float4);

    if (ws_size >= need) {
        int*    counts   = (int*)d_ws;
        float4* buckets  = (float4*)((char*)d_ws + buckets_off);
        float4* overflow = (float4*)((char*)d_ws + overflow_off);

        hipMemsetAsync(counts, 0, (NBUCK + 1) * sizeof(int), stream);
        int pgrid = (n + 255) / 256;
        scatter_kernel<<<pgrid, 256, 0, stream>>>(coords, counts, buckets, overflow, n);
        gather_kernel<<<NBUCK + 32, 256, 0, stream>>>(img, counts, buckets, overflow, out);
    } else {
        int threads = n * 16;
        int grid = (threads + 255) / 256;
        trilerp_kernel<<<grid, 256, 0, stream>>>(img, coords, out, n);
    }
}

// Round 6
// 142.962 us; speedup vs baseline: 1.0532x; 1.0532x over previous
//
#include <hip/hip_runtime.h>

// Trilinear interp of [64,64,64,64] fp32 volume at 200k points.
// R6: R5's bucket-then-tile, but staging uses async global->LDS DMA
// (__builtin_amdgcn_global_load_lds, 16B) -- fire-and-forget 8 chunks per
// wave, single drain at the barrier, instead of 8 serialized load->ds_write
// round-trips. LDS dest = wave-uniform chunk base + lane*16 (HW constraint).

#define NBUCK   4096          // 16^3 buckets of 4^3 voxels
#define CAP     128           // mean occupancy 48.8
#define OVCAP   8192
#define TILE_F4 2048          // 5^3 voxels * 16 float4 = 2000, padded to 2048

typedef float __attribute__((ext_vector_type(4))) fx4;

#define GLOBAL_AS __attribute__((address_space(1)))
#define LDS_AS    __attribute__((address_space(3)))

__device__ __forceinline__ void async_copy16(const float4* g, float4* l) {
    __builtin_amdgcn_global_load_lds(
        (const GLOBAL_AS unsigned int*)(const void*)g,
        (LDS_AS unsigned int*)(void*)l, 16, 0, 0);
}

__device__ __forceinline__ float4 f4mul(float4 a, float s) {
    return make_float4(a.x * s, a.y * s, a.z * s, a.w * s);
}
__device__ __forceinline__ float4 f4fma(float4 a, float s, float4 acc) {
    return make_float4(fmaf(a.x, s, acc.x), fmaf(a.y, s, acc.y),
                       fmaf(a.z, s, acc.z), fmaf(a.w, s, acc.w));
}

__global__ __launch_bounds__(256) void scatter_kernel(
    const float* __restrict__ coords, int* __restrict__ counts,
    float4* __restrict__ buckets, float4* __restrict__ overflow, int n)
{
    int p = blockIdx.x * 256 + threadIdx.x;
    if (p >= n) return;
    float xs = coords[3 * p + 0] * 0.5f;
    float ys = coords[3 * p + 1] * 0.5f;
    float zs = coords[3 * p + 2] * 0.5f;
    int vx = (int)floorf(xs), vy = (int)floorf(ys), vz = (int)floorf(zs);
    int bucket = ((vx >> 2) << 8) | ((vy >> 2) << 4) | (vz >> 2);
    int slot = atomicAdd(&counts[bucket], 1);
    float4 v = make_float4(xs, ys, zs, __int_as_float(p));
    if (slot < CAP) {
        buckets[bucket * CAP + slot] = v;
    } else {
        int o = atomicAdd(&counts[NBUCK], 1);
        if (o < OVCAP) overflow[o] = v;
    }
}

__global__ __launch_bounds__(256) void gather_kernel(
    const float* __restrict__ img, const int* __restrict__ counts,
    const float4* __restrict__ buckets, const float4* __restrict__ overflow,
    float* __restrict__ out)
{
    const float4* __restrict__ imgv = (const float4*)img;
    int cvec = threadIdx.x & 15;
    int grp  = threadIdx.x >> 4;          // 0..15

    if (blockIdx.x < NBUCK) {
        __shared__ float4 tile[TILE_F4];
        // XCD chunk swizzle: 8 XCDs x 512 contiguous buckets each
        int bucket = (blockIdx.x & 7) * 512 + (blockIdx.x >> 3);
        int bx0 = (bucket >> 8) << 2;
        int by0 = ((bucket >> 4) & 15) << 2;
        int bz0 = (bucket & 15) << 2;

        // async-stage 5x5x5 voxel neighborhood: 2048 float4 = 4 waves x 8
        // chunks x 64 lanes. Fire all 8 chunk DMAs, drain once at barrier.
        {
            int wv   = threadIdx.x >> 6;   // wave id 0..3
            int lane = threadIdx.x & 63;
            #pragma unroll
            for (int c = 0; c < 8; c++) {
                int f = ((wv << 3) + c) * 64 + lane;       // 0..2047
                int tv = f >> 4;                           // voxel 0..127
                int ch = f & 15;
                tv = min(tv, 124);                         // pad lanes clamp
                int lx = tv / 25;
                int rem = tv - lx * 25;
                int ly = rem / 5;
                int lz = rem - ly * 5;
                int gx = min(bx0 + lx, 63);
                int gy = min(by0 + ly, 63);
                int gz = min(bz0 + lz, 63);
                const float4* src = &imgv[(((((gx << 6) + gy) << 6) + gz) << 4) + ch];
                async_copy16(src, &tile[((wv << 3) + c) * 64]);
            }
        }
        int cnt = min(counts[bucket], CAP);
        __syncthreads();   // drains vmcnt -> all DMAs landed

        for (int i = grp; i < cnt; i += 16) {
            float4 cs = buckets[bucket * CAP + i];
            float x = cs.x, y = cs.y, z = cs.z;
            int p = __float_as_int(cs.w);

            float fx1 = floorf(x), fx2 = fminf(ceilf(x), 63.0f);
            float fy1 = floorf(y), fy2 = fminf(ceilf(y), 63.0f);
            float fz1 = floorf(z), fz2 = fminf(ceilf(z), 63.0f);

            int lx1 = (int)fx1 - bx0, lx2 = (int)fx2 - bx0;   // 0..4
            int ly1 = (int)fy1 - by0, ly2 = (int)fy2 - by0;
            int lz1 = (int)fz1 - bz0, lz2 = (int)fz2 - bz0;
            int ax1 = lx1 * 25, ax2 = lx2 * 25;
            int ay1 = ly1 * 5,  ay2 = ly2 * 5;

            float4 q111 = tile[((ax1 + ay1 + lz1) << 4) + cvec];
            float4 q211 = tile[((ax2 + ay1 + lz1) << 4) + cvec];
            float4 q121 = tile[((ax1 + ay2 + lz1) << 4) + cvec];
            float4 q221 = tile[((ax2 + ay2 + lz1) << 4) + cvec];
            float4 q112 = tile[((ax1 + ay1 + lz2) << 4) + cvec];
            float4 q212 = tile[((ax2 + ay1 + lz2) << 4) + cvec];
            float4 q122 = tile[((ax1 + ay2 + lz2) << 4) + cvec];
            float4 q222 = tile[((ax2 + ay2 + lz2) << 4) + cvec];

            float wx = x - fx1, wxc = fx2 - x;
            float wy = y - fy1, wyc = fy2 - y;
            float wz = z - fz1, wzc = fz2 - z;

            float4 ly1v = f4fma(f4fma(q221, wx, f4mul(q121, wxc)), wy,
                                f4mul(f4fma(q211, wx, f4mul(q111, wxc)), wyc));
            float4 ly2v = f4fma(f4fma(q222, wx, f4mul(q122, wxc)), wy,
                                f4mul(f4fma(q212, wx, f4mul(q112, wxc)), wyc));
            float4 res = f4fma(ly2v, wz, f4mul(ly1v, wzc));

            fx4 r; r.x = res.x; r.y = res.y; r.z = res.z; r.w = res.w;
            __builtin_nontemporal_store(r, (fx4*)out + (p << 4) + cvec);
        }
    } else {
        // overflow points (normally zero): direct global gather
        int ob = blockIdx.x - NBUCK;            // 0..31
        int cnt = min(counts[NBUCK], OVCAP);
        for (int i = (ob << 4) + grp; i < cnt; i += 32 * 16) {
            float4 cs = overflow[i];
            float x = cs.x, y = cs.y, z = cs.z;
            int p = __float_as_int(cs.w);

            float fx1 = floorf(x), fx2 = fminf(ceilf(x), 63.0f);
            float fy1 = floorf(y), fy2 = fminf(ceilf(y), 63.0f);
            float fz1 = floorf(z), fz2 = fminf(ceilf(z), 63.0f);

            int bx1 = ((int)fx1) << 12, bx2 = ((int)fx2) << 12;
            int by1 = ((int)fy1) << 6,  by2 = ((int)fy2) << 6;
            int iz1 = (int)fz1, iz2 = (int)fz2;

            float4 q111 = imgv[((bx1 + by1 + iz1) << 4) + cvec];
            float4 q211 = imgv[((bx2 + by1 + iz1) << 4) + cvec];
            float4 q121 = imgv[((bx1 + by2 + iz1) << 4) + cvec];
            float4 q221 = imgv[((bx2 + by2 + iz1) << 4) + cvec];
            float4 q112 = imgv[((bx1 + by1 + iz2) << 4) + cvec];
            float4 q212 = imgv[((bx2 + by1 + iz2) << 4) + cvec];
            float4 q122 = imgv[((bx1 + by2 + iz2) << 4) + cvec];
            float4 q222 = imgv[((bx2 + by2 + iz2) << 4) + cvec];

            float wx = x - fx1, wxc = fx2 - x;
            float wy = y - fy1, wyc = fy2 - y;
            float wz = z - fz1, wzc = fz2 - z;

            float4 ly1v = f4fma(f4fma(q221, wx, f4mul(q121, wxc)), wy,
                                f4mul(f4fma(q211, wx, f4mul(q111, wxc)), wyc));
            float4 ly2v = f4fma(f4fma(q222, wx, f4mul(q122, wxc)), wy,
                                f4mul(f4fma(q212, wx, f4mul(q112, wxc)), wyc));
            float4 res = f4fma(ly2v, wz, f4mul(ly1v, wzc));

            fx4 r; r.x = res.x; r.y = res.y; r.z = res.z; r.w = res.w;
            __builtin_nontemporal_store(r, (fx4*)out + (p << 4) + cvec);
        }
    }
}

// Fallback (R1 kernel) if workspace too small.
__global__ __launch_bounds__(256) void trilerp_kernel(
    const float* __restrict__ img, const float* __restrict__ coords,
    float* __restrict__ out, int n_points)
{
    int tid = blockIdx.x * 256 + threadIdx.x;
    int p = tid >> 4;
    if (p >= n_points) return;
    int cvec = tid & 15;

    float x = coords[3 * p + 0] * 0.5f;
    float y = coords[3 * p + 1] * 0.5f;
    float z = coords[3 * p + 2] * 0.5f;

    float fx1 = floorf(x), fx2 = fminf(ceilf(x), 63.0f);
    float fy1 = floorf(y), fy2 = fminf(ceilf(y), 63.0f);
    float fz1 = floorf(z), fz2 = fminf(ceilf(z), 63.0f);

    float wx = x - fx1, wxc = fx2 - x;
    float wy = y - fy1, wyc = fy2 - y;
    float wz = z - fz1, wzc = fz2 - z;

    const float4* __restrict__ imgv = (const float4*)img;
    int bx1 = ((int)fx1) << 12, bx2 = ((int)fx2) << 12;
    int by1 = ((int)fy1) << 6,  by2 = ((int)fy2) << 6;
    int iz1 = (int)fz1, iz2 = (int)fz2;

    float4 q11 = imgv[((bx1 + by1 + iz1) << 4) + cvec];
    float4 q21 = imgv[((bx2 + by1 + iz1) << 4) + cvec];
    float4 q12 = imgv[((bx1 + by2 + iz1) << 4) + cvec];
    float4 q22 = imgv[((bx2 + by2 + iz1) << 4) + cvec];
    float4 ly1 = f4fma(f4fma(q22, wx, f4mul(q12, wxc)), wy,
                       f4mul(f4fma(q21, wx, f4mul(q11, wxc)), wyc));

    q11 = imgv[((bx1 + by1 + iz2) << 4) + cvec];
    q21 = imgv[((bx2 + by1 + iz2) << 4) + cvec];
    q12 = imgv[((bx1 + by2 + iz2) << 4) + cvec];
    q22 = imgv[((bx2 + by2 + iz2) << 4) + cvec];
    float4 ly2 = f4fma(f4fma(q22, wx, f4mul(q12, wxc)), wy,
                       f4mul(f4fma(q21, wx, f4mul(q11, wxc)), wyc));

    float4 res = f4fma(ly2, wz, f4mul(ly1, wzc));
    ((float4*)out)[(p << 4) + cvec] = res;
}

extern "C" void kernel_launch(void* const* d_in, const int* in_sizes, int n_in,
                              void* d_out, int out_size, void* d_ws, size_t ws_size,
                              hipStream_t stream) {
    const float* img    = (const float*)d_in[0];   // [1,64,64,64,64]
    const float* coords = (const float*)d_in[1];   // [1,N,3]
    float* out = (float*)d_out;                    // [1,N,64]
    int n = in_sizes[1] / 3;

    size_t counts_bytes = 32768;                              // 4097 ints, padded
    size_t buckets_off  = counts_bytes;
    size_t buckets_bytes = (size_t)NBUCK * CAP * sizeof(float4);   // 8 MB
    size_t overflow_off = buckets_off + buckets_bytes;
    size_t need = overflow_off + (size_t)OVCAP * sizeof(float4);

    if (ws_size >= need) {
        int*    counts   = (int*)d_ws;
        float4* buckets  = (float4*)((char*)d_ws + buckets_off);
        float4* overflow = (float4*)((char*)d_ws + overflow_off);

        hipMemsetAsync(counts, 0, (NBUCK + 1) * sizeof(int), stream);
        int pgrid = (n + 255) / 256;
        scatter_kernel<<<pgrid, 256, 0, stream>>>(coords, counts, buckets, overflow, n);
        gather_kernel<<<NBUCK + 32, 256, 0, stream>>>(img, counts, buckets, overflow, out);
    } else {
        int threads = n * 16;
        int grid = (threads + 255) / 256;
        trilerp_kernel<<<grid, 256, 0, stream>>>(img, coords, out, n);
    }
}